// Round 18
// baseline (1966.697 us; speedup 1.0000x reference)
//
#include <hip/hip_runtime.h>

// GRU: T=512, B=256, I=H=256, fp32 in/out.
// r16-r18: FUSED producer/consumer. One kernel, 6160 blocks x 512 thr:
//   blocks 0..15   = B-role (recurrence, r15-verbatim + watermark polls)
//   blocks 16..6159 = A-role (gx GEMM, t-major so tile 0 lands first)
// A-role signals per-t completion via release atomicAdd(done[t]) (12 blocks/t);
// B-role confirms with relaxed loads + __threadfence() (acquire) before
// reading the tile. Liveness: B occupies <=16 CUs, A never waits -> no
// deadlock under any dispatch order (G16-safe). r18: BOUNDED spin (cap
// ~16M probes ≈ seconds >> any real wait) — a bug degrades to absmax-fail
// instead of a hang. done[] at d_ws + GX_BYTES (ws_size-guarded; fallback
// = sequential launches). Rule #20: register arrays compile-time-indexed.

typedef float f32x4 __attribute__((ext_vector_type(4)));
typedef short bf16x8 __attribute__((ext_vector_type(8)));

#define GX_SHORTS 100663296          // 768*131072
#define GX_BYTES  201326592

__device__ __forceinline__ unsigned short f2bf(float f) {
  union { float f; unsigned int u; } v; v.f = f;
  unsigned int u = v.u + 0x7fffu + ((v.u >> 16) & 1u);   // RNE
  return (unsigned short)(u >> 16);
}
__device__ __forceinline__ float u2f(unsigned int u) {
  union { unsigned int u; float f; } v; v.u = u; return v.f;
}
__device__ __forceinline__ unsigned int cvt_pk_bf16(float lo, float hi) {
  unsigned int r;
  asm("v_cvt_pk_bf16_f32 %0, %1, %2" : "=v"(r) : "v"(lo), "v"(hi));
  return r;
}
__device__ __forceinline__ float sigmoid_f(float x) {
  return __builtin_amdgcn_rcpf(1.f + __expf(-x));
}
__device__ __forceinline__ float tanh_f(float x) {
  float e = __expf(2.f * x);
  return 1.f - 2.f * __builtin_amdgcn_rcpf(e + 1.f);
}
__device__ __forceinline__ f32x4 unpk(uint2 gv) {
  f32x4 a;
  a[0] = u2f(gv.x << 16); a[1] = u2f(gv.x & 0xffff0000u);
  a[2] = u2f(gv.y << 16); a[3] = u2f(gv.y & 0xffff0000u);
  return a;
}
// col j (0..255), batch b -> short offset in fragment-ordered [kk][lg][16][8]
__device__ __forceinline__ int frag_off(int j, int b) {
  return ((j >> 5) * 64 + ((j >> 3) & 3) * 16 + b) * 8 + (j & 7);
}

// Watermark poll: extend `ready` (highest consecutive tile confirmed done)
// to at least `target`. Relaxed probes batched 8-wide, one acquire fence
// before caller touches tile data. BOUNDED: gives up after ~16M probe
// rounds (orders of magnitude beyond any legitimate wait) so a bug can
// never hang the GPU — it surfaces as an absmax failure instead.
__device__ __forceinline__ int extend_ready(const int* done, int ready, int target) {
  int budget = 1 << 24;
  while (ready < target && budget-- > 0) {
    int v[8];
    #pragma unroll
    for (int i = 0; i < 8; ++i) {
      int idx = ready + 1 + i; if (idx > 511) idx = 511;
      v[i] = __hip_atomic_load(&done[idx], __ATOMIC_RELAXED, __HIP_MEMORY_SCOPE_AGENT);
    }
    int k = 0;
    #pragma unroll
    for (int i = 0; i < 8; ++i) if (i == k && v[i] >= 12) k = i + 1;
    if (k > 0) {
      ready += k; if (ready > 511) ready = 511;
      __threadfence();       // acquire side: invalidate caches before tile reads
    }
  }
  return ready;
}

// ---------------- A role ----------------
// lin in [0,6144): t = lin/12 (ascends with dispatch), sub = lin%12,
// gate = sub>>2, x-quarter = sub&3. 512 threads, lower 256 active.
__device__ void a_role(
    int lin, int tid,
    const float* __restrict__ x,
    const float* __restrict__ Wz, const float* __restrict__ Wr, const float* __restrict__ Wc,
    const float* __restrict__ bz, const float* __restrict__ br, const float* __restrict__ bc,
    unsigned short* __restrict__ gx, int* done)
{
  __shared__ __align__(16) unsigned short As[64][72];    // x tile [m][k]
  __shared__ __align__(16) unsigned short Bs[256][72];   // W tile [j][k], 36KB

  const int t    = lin / 12;
  const int sub  = lin % 12;
  const int gate = sub >> 2;
  const int m0   = t * 256 + (sub & 3) * 64;
  const float* W    = (gate == 0) ? Wz : ((gate == 1) ? Wr : Wc);
  const float* bias = (gate == 0) ? bz : ((gate == 1) ? br : bc);

  const int lane = tid & 63;
  const int wid  = tid >> 6;
  const int l15  = lane & 15;
  const int lg   = lane >> 4;

  f32x4 acc[16];
  #pragma unroll
  for (int n = 0; n < 16; ++n) acc[n] = (f32x4){0.f, 0.f, 0.f, 0.f};

  for (int k0 = 0; k0 < 256; k0 += 64) {
    if (tid < 256) {
      #pragma unroll
      for (int i = 0; i < 4; ++i) {            // x: 64x64
        int idx = tid + i * 256;
        int row = idx >> 4;
        int kq  = (idx & 15) << 2;
        float4 v = *(const float4*)(x + (size_t)(m0 + row) * 256 + k0 + kq);
        uint2 p; p.x = cvt_pk_bf16(v.x, v.y); p.y = cvt_pk_bf16(v.z, v.w);
        *(uint2*)&As[row][kq] = p;
      }
      #pragma unroll
      for (int i = 0; i < 16; ++i) {           // W: 256x64 (x-part cols 256+k)
        int idx = tid + i * 256;
        int row = idx >> 4;
        int kq  = (idx & 15) << 2;
        float4 v = *(const float4*)(W + (size_t)row * 512 + 256 + k0 + kq);
        uint2 p; p.x = cvt_pk_bf16(v.x, v.y); p.y = cvt_pk_bf16(v.z, v.w);
        *(uint2*)&Bs[row][kq] = p;
      }
    }
    __syncthreads();
    if (tid < 256) {
      #pragma unroll
      for (int ks = 0; ks < 64; ks += 32) {
        bf16x8 af = *(const bf16x8*)&As[wid * 16 + l15][ks + lg * 8];
        #pragma unroll
        for (int n = 0; n < 16; ++n) {
          bf16x8 bf = *(const bf16x8*)&Bs[n * 16 + l15][ks + lg * 8];
          acc[n] = __builtin_amdgcn_mfma_f32_16x16x32_bf16(af, bf, acc[n], 0, 0, 0);
        }
      }
    }
    __syncthreads();
  }

  // epilogue: acc + bias -> bf16, stage as Ts[m 64][j 256] (reuse Bs)
  unsigned short* Ts = &Bs[0][0];
  const int TS = 268;
  if (tid < 256) {
    #pragma unroll
    for (int n = 0; n < 16; ++n) {
      const int j = n * 16 + l15;
      float bv = bias[j];
      #pragma unroll
      for (int r = 0; r < 4; ++r) {
        unsigned int pk = cvt_pk_bf16(acc[n][r] + bv, 0.f);
        Ts[(wid * 16 + lg * 4 + r) * TS + j] = (unsigned short)pk;
      }
    }
  }
  __syncthreads();

  const int bg0 = (m0 & 255) >> 4;
  if (tid < 256) {
    #pragma unroll
    for (int i = 0; i < 8; ++i) {
      int idx  = tid + i * 256;     // 0..2047
      int bg_l = idx >> 9;
      int rem  = idx & 511;
      int cb_l = rem >> 3;
      int bp   = rem & 7;
      int m    = bg_l * 16 + bp * 2;
      uint2 lo = *(const uint2*)&Ts[(size_t)m * TS + cb_l * 4];
      uint2 hi = *(const uint2*)&Ts[(size_t)(m + 1) * TS + cb_l * 4];
      uint4 val; val.x = lo.x; val.y = lo.y; val.z = hi.x; val.w = hi.y;
      size_t off = (((size_t)t * 16 + bg0 + bg_l) * 192 + gate * 64 + cb_l) * 64
                   + (size_t)bp * 8;
      *(uint4*)(gx + off) = val;
    }
  }
  __syncthreads();                 // drains stores (vmcnt 0) block-wide
  if (done && tid == 0)
    __hip_atomic_fetch_add(&done[t], 1, __ATOMIC_RELEASE, __HIP_MEMORY_SCOPE_AGENT);
}

// ---------------- B role ---------------- (r15 verbatim + polls)
__device__ void b_role(
    int wg, int tid,
    const unsigned short* __restrict__ gx,
    const float* __restrict__ h0,
    const float* __restrict__ Wz, const float* __restrict__ Wr, const float* __restrict__ Wc,
    float* __restrict__ out, const int* done)
{
  __shared__ __align__(16) unsigned short hA[4096];      // bf16 h, frag-ordered
  __shared__ __align__(16) unsigned short rhA[4096];     // bf16 r*h, frag-ordered

  const int lane  = tid & 63;
  const int wid   = tid >> 6;       // 0..7
  const int l15   = lane & 15;
  const int lg    = lane >> 4;      // 0..3
  const int brow0 = wg * 16;
  const int cb    = wid * 32;       // owned col block

  // ---- persistent weights: bf16 MFMA A-fragments, 3 x 64 = 192 regs ----
  bf16x8 wz[2][8], wr[2][8], wc[2][8];
  #pragma unroll
  for (int n = 0; n < 2; ++n) {
    const int j = cb + n * 16 + l15;
    #pragma unroll
    for (int kk = 0; kk < 8; ++kk) {
      const int k = kk * 32 + lg * 8;
      #pragma unroll
      for (int g = 0; g < 3; ++g) {
        const float* W = (g == 0) ? Wz : ((g == 1) ? Wr : Wc);
        const float* p = W + (size_t)j * 512 + k;      // h-part: cols [0,256)
        float4 a = *(const float4*)p;
        float4 b = *(const float4*)(p + 4);
        bf16x8 f;
        f[0] = (short)f2bf(a.x); f[1] = (short)f2bf(a.y);
        f[2] = (short)f2bf(a.z); f[3] = (short)f2bf(a.w);
        f[4] = (short)f2bf(b.x); f[5] = (short)f2bf(b.y);
        f[6] = (short)f2bf(b.z); f[7] = (short)f2bf(b.w);
        if (g == 0) wz[n][kk] = f; else if (g == 1) wr[n][kk] = f; else wc[n][kk] = f;
      }
    }
  }

  // ---- init h: registers (owned cols) + hA (all cols, bf16 frags) ----
  f32x4 hreg[2];
  #pragma unroll
  for (int n = 0; n < 2; ++n)
    hreg[n] = *(const f32x4*)(h0 + (size_t)(brow0 + l15) * 256 + cb + n * 16 + lg * 4);
  for (int idx = tid; idx < 16 * 256; idx += 512) {
    int r = idx >> 8, c = idx & 255;
    hA[frag_off(c, r)] = f2bf(h0[(size_t)(brow0 + r) * 256 + c]);
  }

  int ready = -1;
  if (done) ready = extend_ready(done, ready, 0);   // tile 0 must be done

  // ---- prefetch t=0 gx into registers (6 x uint2) ----
  uint2 g1z[2], g1r[2], g2[2];
  {
    const size_t tb = (size_t)wg * 12288;
    #pragma unroll
    for (int n = 0; n < 2; ++n) {
      g1z[n] = *(const uint2*)(gx + tb + (size_t)(wid * 8 + n * 4 + lg) * 64 + l15 * 4);
      g1r[n] = *(const uint2*)(gx + tb + (size_t)(64 + wid * 8 + n * 4 + lg) * 64 + l15 * 4);
      g2[n]  = *(const uint2*)(gx + tb + (size_t)(128 + wid * 8 + n * 4 + lg) * 64 + l15 * 4);
    }
  }
  __syncthreads();   // hA visible

  for (int t = 0; t < 512; ++t) {
    const int tn = (t < 511) ? (t + 1) : 511;
    const size_t tbn = ((size_t)tn * 16 + wg) * 12288;

    if (done) ready = extend_ready(done, ready, tn);   // tile tn before prefetch

    // ---------- phase 1: z and r (two independent MFMA chains) ----------
    f32x4 accZ[2], accR[2];
    #pragma unroll
    for (int n = 0; n < 2; ++n) { accZ[n] = unpk(g1z[n]); accR[n] = unpk(g1r[n]); }
    // issue next-step prefetch (full step to land)
    #pragma unroll
    for (int n = 0; n < 2; ++n) {
      g1z[n] = *(const uint2*)(gx + tbn + (size_t)(wid * 8 + n * 4 + lg) * 64 + l15 * 4);
      g1r[n] = *(const uint2*)(gx + tbn + (size_t)(64 + wid * 8 + n * 4 + lg) * 64 + l15 * 4);
    }

    #pragma unroll
    for (int kk = 0; kk < 8; ++kk) {   // compile-time kk (rule #20)
      bf16x8 hf = *(const bf16x8*)&hA[kk * 512 + lane * 8];   // linear, 0-conflict
      accZ[0] = __builtin_amdgcn_mfma_f32_16x16x32_bf16(wz[0][kk], hf, accZ[0], 0, 0, 0);
      accZ[1] = __builtin_amdgcn_mfma_f32_16x16x32_bf16(wz[1][kk], hf, accZ[1], 0, 0, 0);
      accR[0] = __builtin_amdgcn_mfma_f32_16x16x32_bf16(wr[0][kk], hf, accR[0], 0, 0, 0);
      accR[1] = __builtin_amdgcn_mfma_f32_16x16x32_bf16(wr[1][kk], hf, accR[1], 0, 0, 0);
    }
    f32x4 zreg[2];
    #pragma unroll
    for (int n = 0; n < 2; ++n) {
      #pragma unroll
      for (int r = 0; r < 4; ++r) zreg[n][r] = sigmoid_f(accZ[n][r]);
      float rh0 = sigmoid_f(accR[n][0]) * hreg[n][0];
      float rh1 = sigmoid_f(accR[n][1]) * hreg[n][1];
      float rh2 = sigmoid_f(accR[n][2]) * hreg[n][2];
      float rh3 = sigmoid_f(accR[n][3]) * hreg[n][3];
      uint2 pk; pk.x = cvt_pk_bf16(rh0, rh1); pk.y = cvt_pk_bf16(rh2, rh3);
      *(uint2*)&rhA[frag_off(cb + n * 16 + lg * 4, l15)] = pk;
    }
    // raw barrier: LDS ordering only, never drain vmcnt in the loop
    asm volatile("s_waitcnt lgkmcnt(0)" ::: "memory");
    __builtin_amdgcn_s_barrier();
    __builtin_amdgcn_sched_barrier(0);

    // ---------- phase 2: cand + register h update ----------
    f32x4 acc2[2];
    #pragma unroll
    for (int n = 0; n < 2; ++n) acc2[n] = unpk(g2[n]);
    #pragma unroll
    for (int n = 0; n < 2; ++n)
      g2[n] = *(const uint2*)(gx + tbn + (size_t)(128 + wid * 8 + n * 4 + lg) * 64 + l15 * 4);

    #pragma unroll
    for (int kk = 0; kk < 8; ++kk) {   // compile-time kk
      bf16x8 rf = *(const bf16x8*)&rhA[kk * 512 + lane * 8];  // linear, 0-conflict
      acc2[0] = __builtin_amdgcn_mfma_f32_16x16x32_bf16(wc[0][kk], rf, acc2[0], 0, 0, 0);
      acc2[1] = __builtin_amdgcn_mfma_f32_16x16x32_bf16(wc[1][kk], rf, acc2[1], 0, 0, 0);
    }
    #pragma unroll
    for (int n = 0; n < 2; ++n) {
      #pragma unroll
      for (int r = 0; r < 4; ++r) {
        float th = tanh_f(acc2[n][r]);
        hreg[n][r] = hreg[n][r] + zreg[n][r] * (th - hreg[n][r]);
      }
      *(f32x4*)(out + (size_t)t * 65536 + (size_t)(brow0 + l15) * 256 + cb + n * 16 + lg * 4) = hreg[n];
      if (t == 511)
        *(f32x4*)(out + (size_t)33554432 + (size_t)(brow0 + l15) * 256 + cb + n * 16 + lg * 4) = hreg[n];
      uint2 pk; pk.x = cvt_pk_bf16(hreg[n][0], hreg[n][1]);
      pk.y = cvt_pk_bf16(hreg[n][2], hreg[n][3]);
      *(uint2*)&hA[frag_off(cb + n * 16 + lg * 4, l15)] = pk;
    }
    asm volatile("s_waitcnt lgkmcnt(0)" ::: "memory");
    __builtin_amdgcn_s_barrier();
    __builtin_amdgcn_sched_barrier(0);
  }
}

// ---------------- kernels ----------------
__global__ __launch_bounds__(512, 1) void gru_fused_kernel(
    const float* __restrict__ x, const float* __restrict__ h0,
    const float* __restrict__ Wz, const float* __restrict__ Wr, const float* __restrict__ Wc,
    const float* __restrict__ bz, const float* __restrict__ br, const float* __restrict__ bc,
    unsigned short* __restrict__ gx, float* __restrict__ out, int* done)
{
  if (blockIdx.x < 16)
    b_role(blockIdx.x, threadIdx.x, gx, h0, Wz, Wr, Wc, out, done);
  else
    a_role(blockIdx.x - 16, threadIdx.x, x, Wz, Wr, Wc, bz, br, bc, gx, done);
}

__global__ __launch_bounds__(512, 1) void gru_gx_kernel(
    const float* __restrict__ x,
    const float* __restrict__ Wz, const float* __restrict__ Wr, const float* __restrict__ Wc,
    const float* __restrict__ bz, const float* __restrict__ br, const float* __restrict__ bc,
    unsigned short* __restrict__ gx)
{
  a_role(blockIdx.x, threadIdx.x, x, Wz, Wr, Wc, bz, br, bc, gx, nullptr);
}

__global__ __launch_bounds__(512, 1) void gru_rec_kernel(
    const unsigned short* __restrict__ gx,
    const float* __restrict__ h0,
    const float* __restrict__ Wz, const float* __restrict__ Wr, const float* __restrict__ Wc,
    float* __restrict__ out)
{
  b_role(blockIdx.x, threadIdx.x, gx, h0, Wz, Wr, Wc, out, nullptr);
}

extern "C" void kernel_launch(void* const* d_in, const int* in_sizes, int n_in,
                              void* d_out, int out_size, void* d_ws, size_t ws_size,
                              hipStream_t stream) {
  const float* x  = (const float*)d_in[0];
  const float* h0 = (const float*)d_in[1];
  const float* Wz = (const float*)d_in[2];
  const float* bz = (const float*)d_in[3];
  const float* Wr = (const float*)d_in[4];
  const float* br = (const float*)d_in[5];
  const float* Wc = (const float*)d_in[6];
  const float* bc = (const float*)d_in[7];
  float* out = (float*)d_out;
  unsigned short* gxbuf = (unsigned short*)d_ws;   // 201.3 MB

  if (ws_size >= (size_t)GX_BYTES + 4096) {
    int* done = (int*)((char*)d_ws + GX_BYTES);
    hipMemsetAsync(done, 0, 2048, stream);
    gru_fused_kernel<<<6160, 512, 0, stream>>>(x, h0, Wz, Wr, Wc, bz, br, bc,
                                               gxbuf, out, done);
  } else {
    gru_gx_kernel<<<6144, 512, 0, stream>>>(x, Wz, Wr, Wc, bz, br, bc, gxbuf);
    gru_rec_kernel<<<16, 512, 0, stream>>>(gxbuf, h0, Wz, Wr, Wc, out);
  }
}

// Round 19
// 1041.825 us; speedup vs baseline: 1.8877x; 1.8877x over previous
//
#include <hip/hip_runtime.h>

// GRU: T=512, B=256, I=H=256, fp32 in/out.  == r15 verbatim (best: 1041us) ==
// Stage A (parallel GEMM): grid (2048,3) — one GATE per blockIdx.y,
//   tile 64M x 256N, K=256 in 4 chunks; x staged once per chunk; f32->bf16
//   via v_cvt_pk_bf16_f32; bias folded.
//   Layout: gx[tile = t*16+bg][colblk 0..191][batch 0..15][colin 0..3], bf16.
// Stage B (recurrent): 16 WGs x 512 thr (8 waves); wave w owns cols
//   [32w,32w+32) for z,r,cand; z,h in registers; weights persistent
//   (192 regs); frag-ordered hA/rhA (0-conflict ds_read_b128); direct-reg
//   gx prefetch 1 step ahead; raw lgkmcnt-only barriers.
// r18 lesson: A/B fusion (producer/consumer spin) regressed 1041->1991 us —
//   A-role blocks co-resident on B's CUs contend with the serial chain, and
//   agent-scope polls + threadfence add per-step latency. Reverted.
// Rule #20: all register arrays indexed by compile-time constants only.

typedef float f32x4 __attribute__((ext_vector_type(4)));
typedef short bf16x8 __attribute__((ext_vector_type(8)));

__device__ __forceinline__ unsigned short f2bf(float f) {
  union { float f; unsigned int u; } v; v.f = f;
  unsigned int u = v.u + 0x7fffu + ((v.u >> 16) & 1u);   // RNE
  return (unsigned short)(u >> 16);
}
__device__ __forceinline__ float u2f(unsigned int u) {
  union { unsigned int u; float f; } v; v.u = u; return v.f;
}
__device__ __forceinline__ unsigned int cvt_pk_bf16(float lo, float hi) {
  unsigned int r;
  asm("v_cvt_pk_bf16_f32 %0, %1, %2" : "=v"(r) : "v"(lo), "v"(hi));
  return r;
}
__device__ __forceinline__ float sigmoid_f(float x) {
  return __builtin_amdgcn_rcpf(1.f + __expf(-x));
}
__device__ __forceinline__ float tanh_f(float x) {
  float e = __expf(2.f * x);
  return 1.f - 2.f * __builtin_amdgcn_rcpf(e + 1.f);
}
__device__ __forceinline__ f32x4 unpk(uint2 gv) {
  f32x4 a;
  a[0] = u2f(gv.x << 16); a[1] = u2f(gv.x & 0xffff0000u);
  a[2] = u2f(gv.y << 16); a[3] = u2f(gv.y & 0xffff0000u);
  return a;
}
// col j (0..255), batch b -> short offset in fragment-ordered [kk][lg][16][8]
__device__ __forceinline__ int frag_off(int j, int b) {
  return ((j >> 5) * 64 + ((j >> 3) & 3) * 16 + b) * 8 + (j & 7);
}

// ---------------- Stage A ----------------
// grid (2048, 3), block 256 (4 waves). Tile 64M x 256N (one gate), K=256.
__global__ __launch_bounds__(256) void gru_gx_kernel(
    const float* __restrict__ x,
    const float* __restrict__ Wz, const float* __restrict__ Wr, const float* __restrict__ Wc,
    const float* __restrict__ bz, const float* __restrict__ br, const float* __restrict__ bc,
    unsigned short* __restrict__ gx)
{
  __shared__ __align__(16) unsigned short As[64][72];    // x tile [m][k], +8 pad
  __shared__ __align__(16) unsigned short Bs[256][72];   // W tile [j][k], 36KB

  const int tid  = threadIdx.x;
  const int lane = tid & 63;
  const int wid  = tid >> 6;       // 0..3
  const int l15  = lane & 15;
  const int lg   = lane >> 4;      // 0..3
  const int m0   = blockIdx.x * 64;      // m = t*256 + b
  const int gate = blockIdx.y;           // 0=z 1=r 2=cand
  const float* W    = (gate == 0) ? Wz : ((gate == 1) ? Wr : Wc);
  const float* bias = (gate == 0) ? bz : ((gate == 1) ? br : bc);

  f32x4 acc[16];
  #pragma unroll
  for (int n = 0; n < 16; ++n) acc[n] = (f32x4){0.f, 0.f, 0.f, 0.f};

  for (int k0 = 0; k0 < 256; k0 += 64) {
    #pragma unroll
    for (int i = 0; i < 4; ++i) {            // x: 64x64
      int idx = tid + i * 256;               // 0..1023
      int row = idx >> 4;
      int kq  = (idx & 15) << 2;
      float4 v = *(const float4*)(x + (size_t)(m0 + row) * 256 + k0 + kq);
      uint2 p; p.x = cvt_pk_bf16(v.x, v.y); p.y = cvt_pk_bf16(v.z, v.w);
      *(uint2*)&As[row][kq] = p;
    }
    #pragma unroll
    for (int i = 0; i < 16; ++i) {           // W: 256x64 (x-part cols 256+k)
      int idx = tid + i * 256;               // 0..4095
      int row = idx >> 4;
      int kq  = (idx & 15) << 2;
      float4 v = *(const float4*)(W + (size_t)row * 512 + 256 + k0 + kq);
      uint2 p; p.x = cvt_pk_bf16(v.x, v.y); p.y = cvt_pk_bf16(v.z, v.w);
      *(uint2*)&Bs[row][kq] = p;
    }
    __syncthreads();
    #pragma unroll
    for (int ks = 0; ks < 64; ks += 32) {
      bf16x8 af = *(const bf16x8*)&As[wid * 16 + l15][ks + lg * 8];
      #pragma unroll
      for (int n = 0; n < 16; ++n) {
        bf16x8 bf = *(const bf16x8*)&Bs[n * 16 + l15][ks + lg * 8];
        acc[n] = __builtin_amdgcn_mfma_f32_16x16x32_bf16(af, bf, acc[n], 0, 0, 0);
      }
    }
    __syncthreads();
  }

  // epilogue: acc + bias -> bf16, stage as Ts[m 64][j 256] (reuse Bs)
  unsigned short* Ts = &Bs[0][0];            // stride 268 shorts (8B-aligned rows)
  const int TS = 268;
  #pragma unroll
  for (int n = 0; n < 16; ++n) {
    const int j = n * 16 + l15;
    float bv = bias[j];
    #pragma unroll
    for (int r = 0; r < 4; ++r) {
      unsigned int pk = cvt_pk_bf16(acc[n][r] + bv, 0.f);
      Ts[(wid * 16 + lg * 4 + r) * TS + j] = (unsigned short)pk;
    }
  }
  __syncthreads();

  const int tt  = m0 >> 8;        // t (tile spans one t since 64 | 256)
  const int bg0 = (m0 & 255) >> 4;
  #pragma unroll
  for (int i = 0; i < 8; ++i) {
    int idx  = tid + i * 256;     // 0..2047
    int bg_l = idx >> 9;          // 0..3
    int rem  = idx & 511;
    int cb_l = rem >> 3;          // 0..63 (colblk within gate)
    int bp   = rem & 7;           // batch pair
    int m    = bg_l * 16 + bp * 2;
    uint2 lo = *(const uint2*)&Ts[(size_t)m * TS + cb_l * 4];
    uint2 hi = *(const uint2*)&Ts[(size_t)(m + 1) * TS + cb_l * 4];
    uint4 val; val.x = lo.x; val.y = lo.y; val.z = hi.x; val.w = hi.y;
    size_t off = (((size_t)tt * 16 + bg0 + bg_l) * 192 + gate * 64 + cb_l) * 64
                 + (size_t)bp * 8;   // shorts
    *(uint4*)(gx + off) = val;
  }
}

// ---------------- Stage B ----------------
// grid 16, block 512 (8 waves). WG wg owns batch rows [16wg, 16wg+16).
// Wave w owns output cols [32w, 32w+32) for z, r, and cand.
__global__ __launch_bounds__(512, 1) void gru_rec_kernel(
    const unsigned short* __restrict__ gx,
    const float* __restrict__ h0,
    const float* __restrict__ Wz, const float* __restrict__ Wr, const float* __restrict__ Wc,
    float* __restrict__ out)
{
  __shared__ __align__(16) unsigned short hA[4096];      // bf16 h, frag-ordered
  __shared__ __align__(16) unsigned short rhA[4096];     // bf16 r*h, frag-ordered

  const int tid   = threadIdx.x;
  const int lane  = tid & 63;
  const int wid   = tid >> 6;       // 0..7
  const int l15   = lane & 15;
  const int lg    = lane >> 4;      // 0..3
  const int wg    = blockIdx.x;
  const int brow0 = wg * 16;
  const int cb    = wid * 32;       // owned col block

  // ---- persistent weights: bf16 MFMA A-fragments, 3 x 64 = 192 regs ----
  bf16x8 wz[2][8], wr[2][8], wc[2][8];
  #pragma unroll
  for (int n = 0; n < 2; ++n) {
    const int j = cb + n * 16 + l15;
    #pragma unroll
    for (int kk = 0; kk < 8; ++kk) {
      const int k = kk * 32 + lg * 8;
      #pragma unroll
      for (int g = 0; g < 3; ++g) {
        const float* W = (g == 0) ? Wz : ((g == 1) ? Wr : Wc);
        const float* p = W + (size_t)j * 512 + k;      // h-part: cols [0,256)
        float4 a = *(const float4*)p;
        float4 b = *(const float4*)(p + 4);
        bf16x8 f;
        f[0] = (short)f2bf(a.x); f[1] = (short)f2bf(a.y);
        f[2] = (short)f2bf(a.z); f[3] = (short)f2bf(a.w);
        f[4] = (short)f2bf(b.x); f[5] = (short)f2bf(b.y);
        f[6] = (short)f2bf(b.z); f[7] = (short)f2bf(b.w);
        if (g == 0) wz[n][kk] = f; else if (g == 1) wr[n][kk] = f; else wc[n][kk] = f;
      }
    }
  }

  // ---- init h: registers (owned cols) + hA (all cols, bf16 frags) ----
  f32x4 hreg[2];
  #pragma unroll
  for (int n = 0; n < 2; ++n)
    hreg[n] = *(const f32x4*)(h0 + (size_t)(brow0 + l15) * 256 + cb + n * 16 + lg * 4);
  for (int idx = tid; idx < 16 * 256; idx += 512) {
    int r = idx >> 8, c = idx & 255;
    hA[frag_off(c, r)] = f2bf(h0[(size_t)(brow0 + r) * 256 + c]);
  }

  // ---- prefetch t=0 gx into registers (6 x uint2) ----
  uint2 g1z[2], g1r[2], g2[2];
  {
    const size_t tb = (size_t)wg * 12288;
    #pragma unroll
    for (int n = 0; n < 2; ++n) {
      g1z[n] = *(const uint2*)(gx + tb + (size_t)(wid * 8 + n * 4 + lg) * 64 + l15 * 4);
      g1r[n] = *(const uint2*)(gx + tb + (size_t)(64 + wid * 8 + n * 4 + lg) * 64 + l15 * 4);
      g2[n]  = *(const uint2*)(gx + tb + (size_t)(128 + wid * 8 + n * 4 + lg) * 64 + l15 * 4);
    }
  }
  __syncthreads();   // hA visible

  for (int t = 0; t < 512; ++t) {
    const int tn = (t < 511) ? (t + 1) : 511;
    const size_t tbn = ((size_t)tn * 16 + wg) * 12288;

    // ---------- phase 1: z and r (two independent MFMA chains) ----------
    f32x4 accZ[2], accR[2];
    #pragma unroll
    for (int n = 0; n < 2; ++n) { accZ[n] = unpk(g1z[n]); accR[n] = unpk(g1r[n]); }
    // issue next-step prefetch (full step to land)
    #pragma unroll
    for (int n = 0; n < 2; ++n) {
      g1z[n] = *(const uint2*)(gx + tbn + (size_t)(wid * 8 + n * 4 + lg) * 64 + l15 * 4);
      g1r[n] = *(const uint2*)(gx + tbn + (size_t)(64 + wid * 8 + n * 4 + lg) * 64 + l15 * 4);
    }

    #pragma unroll
    for (int kk = 0; kk < 8; ++kk) {   // compile-time kk (rule #20)
      bf16x8 hf = *(const bf16x8*)&hA[kk * 512 + lane * 8];   // linear, 0-conflict
      accZ[0] = __builtin_amdgcn_mfma_f32_16x16x32_bf16(wz[0][kk], hf, accZ[0], 0, 0, 0);
      accZ[1] = __builtin_amdgcn_mfma_f32_16x16x32_bf16(wz[1][kk], hf, accZ[1], 0, 0, 0);
      accR[0] = __builtin_amdgcn_mfma_f32_16x16x32_bf16(wr[0][kk], hf, accR[0], 0, 0, 0);
      accR[1] = __builtin_amdgcn_mfma_f32_16x16x32_bf16(wr[1][kk], hf, accR[1], 0, 0, 0);
    }
    f32x4 zreg[2];
    #pragma unroll
    for (int n = 0; n < 2; ++n) {
      #pragma unroll
      for (int r = 0; r < 4; ++r) zreg[n][r] = sigmoid_f(accZ[n][r]);
      float rh0 = sigmoid_f(accR[n][0]) * hreg[n][0];
      float rh1 = sigmoid_f(accR[n][1]) * hreg[n][1];
      float rh2 = sigmoid_f(accR[n][2]) * hreg[n][2];
      float rh3 = sigmoid_f(accR[n][3]) * hreg[n][3];
      uint2 pk; pk.x = cvt_pk_bf16(rh0, rh1); pk.y = cvt_pk_bf16(rh2, rh3);
      *(uint2*)&rhA[frag_off(cb + n * 16 + lg * 4, l15)] = pk;
    }
    // raw barrier: LDS ordering only, never drain vmcnt in the loop
    asm volatile("s_waitcnt lgkmcnt(0)" ::: "memory");
    __builtin_amdgcn_s_barrier();
    __builtin_amdgcn_sched_barrier(0);

    // ---------- phase 2: cand + register h update ----------
    f32x4 acc2[2];
    #pragma unroll
    for (int n = 0; n < 2; ++n) acc2[n] = unpk(g2[n]);
    #pragma unroll
    for (int n = 0; n < 2; ++n)
      g2[n] = *(const uint2*)(gx + tbn + (size_t)(128 + wid * 8 + n * 4 + lg) * 64 + l15 * 4);

    #pragma unroll
    for (int kk = 0; kk < 8; ++kk) {   // compile-time kk
      bf16x8 rf = *(const bf16x8*)&rhA[kk * 512 + lane * 8];  // linear, 0-conflict
      acc2[0] = __builtin_amdgcn_mfma_f32_16x16x32_bf16(wc[0][kk], rf, acc2[0], 0, 0, 0);
      acc2[1] = __builtin_amdgcn_mfma_f32_16x16x32_bf16(wc[1][kk], rf, acc2[1], 0, 0, 0);
    }
    #pragma unroll
    for (int n = 0; n < 2; ++n) {
      #pragma unroll
      for (int r = 0; r < 4; ++r) {
        float th = tanh_f(acc2[n][r]);
        hreg[n][r] = hreg[n][r] + zreg[n][r] * (th - hreg[n][r]);
      }
      *(f32x4*)(out + (size_t)t * 65536 + (size_t)(brow0 + l15) * 256 + cb + n * 16 + lg * 4) = hreg[n];
      if (t == 511)
        *(f32x4*)(out + (size_t)33554432 + (size_t)(brow0 + l15) * 256 + cb + n * 16 + lg * 4) = hreg[n];
      uint2 pk; pk.x = cvt_pk_bf16(hreg[n][0], hreg[n][1]);
      pk.y = cvt_pk_bf16(hreg[n][2], hreg[n][3]);
      *(uint2*)&hA[frag_off(cb + n * 16 + lg * 4, l15)] = pk;
    }
    asm volatile("s_waitcnt lgkmcnt(0)" ::: "memory");
    __builtin_amdgcn_s_barrier();
    __builtin_amdgcn_sched_barrier(0);
  }
}

extern "C" void kernel_launch(void* const* d_in, const int* in_sizes, int n_in,
                              void* d_out, int out_size, void* d_ws, size_t ws_size,
                              hipStream_t stream) {
  const float* x  = (const float*)d_in[0];
  const float* h0 = (const float*)d_in[1];
  const float* Wz = (const float*)d_in[2];
  const float* bz = (const float*)d_in[3];
  const float* Wr = (const float*)d_in[4];
  const float* br = (const float*)d_in[5];
  const float* Wc = (const float*)d_in[6];
  const float* bc = (const float*)d_in[7];
  float* out = (float*)d_out;
  unsigned short* gxbuf = (unsigned short*)d_ws;   // 768*131072*2 = 201.3 MB

  dim3 gridA(2048, 3);
  gru_gx_kernel<<<gridA, 256, 0, stream>>>(x, Wz, Wr, Wc, bz, br, bc, gxbuf);
  gru_rec_kernel<<<16, 512, 0, stream>>>(gxbuf, h0, Wz, Wr, Wc, out);
}